// Round 9
// baseline (90.833 us; speedup 1.0000x reference)
//
#include <hip/hip_runtime.h>

#define NCH 24
#define KS 11
#define TH 32          // output rows per tile
#define TW 64          // output cols per tile
#define IWC 76         // LDS col stride (>= TW+10+2, mult of 4)

typedef float vbuf_t[TH][IWC];   // one field: 32 x 76

// ===== vertical pass: sep-conv (4 fields) global->reg->LDS, NO barrier ====
// fields: 0 = x, 1 = y, 2 = xx+yy, 3 = xy
template<bool GUARD>
__device__ __forceinline__ void v_pass(
    const float* __restrict__ Xp, const float* __restrict__ Yp,
    const float* __restrict__ k, int H, int W, int gx0, int gy0, int tid,
    vbuf_t* vbuf)
{
    if (tid < 3 * IWC) {
        const int c  = tid % IWC;
        const int rg = tid / IWC;
        const int r0 = rg * 11;
        const int gc = gx0 + c;
        const bool cok = (!GUARD) || (gc < W);

        float acc[11][4];
#pragma unroll
        for (int i = 0; i < 11; ++i)
#pragma unroll
            for (int f = 0; f < 4; ++f) acc[i][f] = 0.f;

        const float* xptr = Xp + (size_t)(gy0 + r0) * W + gc;
        const float* yptr = Yp + (size_t)(gy0 + r0) * W + gc;

#pragma unroll
        for (int ri = 0; ri < 21; ++ri) {
            float xv, yv;
            if (GUARD) {
                const int gy = gy0 + r0 + ri;
                xv = 0.f; yv = 0.f;
                if (cok && gy < H) { xv = xptr[0]; yv = yptr[0]; }
            } else {
                xv = xptr[0]; yv = yptr[0];
            }
            xptr += W; yptr += W;
            const float sq = fmaf(yv, yv, xv * xv);
            const float xy = xv * yv;
#pragma unroll
            for (int rv = 0; rv < 11; ++rv) {
                if (rv < (ri > 10 ? ri - 10 : 0)) continue;
                if (rv > (ri < 10 ? ri : 10)) continue;
                const float kt = k[ri - rv];
                acc[rv][0] += kt * xv;
                acc[rv][1] += kt * yv;
                acc[rv][2] += kt * sq;
                acc[rv][3] += kt * xy;
            }
        }
#pragma unroll
        for (int rv = 0; rv < 11; ++rv) {
            const int r = r0 + rv;
            if (r < TH) {
#pragma unroll
                for (int f = 0; f < 4; ++f)
                    vbuf[f][r][c] = acc[rv][f];
            }
        }
    }
}

// ===== scale-0 v-pass WITH in-register pooling (no global re-read) ========
// rg0 owns pooled rows 0-9 (input rows 0..19); rg1 rows 10-15 (rows 20..31).
// Col pairs via shfl_down(1) (even-c pairs never cross wave boundary);
// lvl2 col pairs via shfl_down(2) (readers at lane%4==0, never cross).
template<bool GUARD>
__device__ __forceinline__ void v_pass_pool(
    const float* __restrict__ Xp, const float* __restrict__ Yp,
    const float* __restrict__ k, int gx0, int gy0, int tid,
    vbuf_t* vbuf, float (*pl2)[8][16],
    float* __restrict__ X1, float* __restrict__ Y1,
    float* __restrict__ X2, float* __restrict__ Y2, int nc)
{
    const int W = 512, H = 512;
    if (tid < 3 * IWC) {
        const int c  = tid % IWC;
        const int rg = tid / IWC;
        const int r0 = rg * 11;
        const int gc = gx0 + c;
        const bool cok = (!GUARD) || (gc < W);

        float acc[11][4];
#pragma unroll
        for (int i = 0; i < 11; ++i)
#pragma unroll
            for (int f = 0; f < 4; ++f) acc[i][f] = 0.f;
        float px[10], py[10];
#pragma unroll
        for (int i = 0; i < 10; ++i) { px[i] = 0.f; py[i] = 0.f; }

        const float* xptr = Xp + (size_t)(gy0 + r0) * W + gc;
        const float* yptr = Yp + (size_t)(gy0 + r0) * W + gc;

#pragma unroll
        for (int ri = 0; ri < 21; ++ri) {
            float xv, yv;
            if (GUARD) {
                const int gy = gy0 + r0 + ri;
                xv = 0.f; yv = 0.f;
                if (cok && gy < H) { xv = xptr[0]; yv = yptr[0]; }
            } else {
                xv = xptr[0]; yv = yptr[0];
            }
            xptr += W; yptr += W;

            // ---- pooling row-pair accumulation (static indices) ----
            if (rg == 0) {
                if (ri < 20) { px[ri >> 1] += xv; py[ri >> 1] += yv; }
            } else if (rg == 1) {
                if (ri >= 9) { px[(ri - 9) >> 1] += xv; py[(ri - 9) >> 1] += yv; }
            }

            const float sq = fmaf(yv, yv, xv * xv);
            const float xy = xv * yv;
#pragma unroll
            for (int rv = 0; rv < 11; ++rv) {
                if (rv < (ri > 10 ? ri - 10 : 0)) continue;
                if (rv > (ri < 10 ? ri : 10)) continue;
                const float kt = k[ri - rv];
                acc[rv][0] += kt * xv;
                acc[rv][1] += kt * yv;
                acc[rv][2] += kt * sq;
                acc[rv][3] += kt * xy;
            }
        }
#pragma unroll
        for (int rv = 0; rv < 11; ++rv) {
            const int r = r0 + rv;
            if (r < TH) {
#pragma unroll
                for (int f = 0; f < 4; ++f)
                    vbuf[f][r][c] = acc[rv][f];
            }
        }

        // ---- pooled level 1 (16x32): col combine, even-c writes ----
        const int W2 = 256, W4 = 128;
#pragma unroll
        for (int j = 0; j < 10; ++j) {
            float sx = px[j] + __shfl_down(px[j], 1);
            float sy = py[j] + __shfl_down(py[j], 1);
            px[j] = sx; py[j] = sy;     // keep 2x2 sums for lvl2
            if (((c & 1) == 0) && (c < 64) && (rg == 0 || (rg == 1 && j < 6))) {
                int pr = (rg == 0) ? j : 10 + j;
                size_t d1 = (size_t)nc * W2 * W2 + (size_t)((gy0 >> 1) + pr) * W2 + ((gx0 >> 1) + (c >> 1));
                X1[d1] = 0.25f * sx;
                Y1[d1] = 0.25f * sy;
            }
        }
        // ---- pooled level 2 (8x16): in-thread row pairs + shfl_down(2) ----
#pragma unroll
        for (int q = 0; q < 5; ++q) {
            float s2x = px[2 * q] + px[2 * q + 1];
            float s2y = py[2 * q] + py[2 * q + 1];
            s2x += __shfl_down(s2x, 2);
            s2y += __shfl_down(s2y, 2);
            if (((c & 3) == 0) && (c < 64) && (rg == 0 ? (q < 5) : (rg == 1 && q < 3))) {
                int r2 = (rg == 0) ? q : 5 + q;
                int c2 = c >> 2;
                float vx = s2x * 0.0625f, vy = s2y * 0.0625f;
                pl2[0][r2][c2] = vx;  pl2[1][r2][c2] = vy;
                size_t d2 = (size_t)nc * W4 * W4 + (size_t)((gy0 >> 2) + r2) * W4 + ((gx0 >> 2) + c2);
                X2[d2] = vx;  Y2[d2] = vy;
            }
        }
    }
}

// ===== horizontal pass: b128 LDS reads + SSIM (call after barrier) ========
template<bool GUARD>
__device__ __forceinline__ void h_pass(
    const float* __restrict__ k, int H, int W, int gx0, int gy0, int tid,
    vbuf_t* vbuf, float& ss_acc, float& cs_acc)
{
    const float c1 = 1e-4f, c2 = 9e-4f;
    const int row = tid >> 3;
    const int cg  = tid & 7;
    const int c0  = cg * 8;
    const bool rowok = (!GUARD) || ((gy0 + row) <= (H - KS));

    float hacc[4][8];
#pragma unroll
    for (int f = 0; f < 4; ++f)
#pragma unroll
        for (int j = 0; j < 8; ++j) hacc[f][j] = 0.f;

#pragma unroll
    for (int f = 0; f < 4; ++f) {
        const float4* vp = reinterpret_cast<const float4*>(&vbuf[f][row][c0]);
        float4 q0 = vp[0], q1 = vp[1], q2 = vp[2], q3 = vp[3], q4 = vp[4];
        float v[20] = {q0.x,q0.y,q0.z,q0.w, q1.x,q1.y,q1.z,q1.w,
                       q2.x,q2.y,q2.z,q2.w, q3.x,q3.y,q3.z,q3.w,
                       q4.x,q4.y,q4.z,q4.w};
#pragma unroll
        for (int j = 0; j < 8; ++j)
#pragma unroll
            for (int t = 0; t < KS; ++t)
                hacc[f][j] += k[t] * v[j + t];
    }

#pragma unroll
    for (int j = 0; j < 8; ++j) {
        bool ok = rowok && ((!GUARD) || ((gx0 + c0 + j) <= (W - KS)));
        if (ok) {
            float mx = hacc[0][j], my = hacc[1][j];
            float S = hacc[2][j], vxy = hacc[3][j];
            float mxx = mx * mx, myy = my * my, mxy = mx * my;
            float msum = mxx + myy;
            float sxy = vxy - mxy, ssum = S - msum;
            float cs = (2.f * sxy + c2) * __builtin_amdgcn_rcpf(ssum + c2);
            float ssv = (2.f * mxy + c1) * __builtin_amdgcn_rcpf(msum + c1) * cs;
            ss_acc += ssv; cs_acc += cs;
        }
    }
}

__device__ __forceinline__ void block_reduce_store(
    float ss_acc, float cs_acc, int tid, float* red, float* slot)
{
    for (int off = 32; off > 0; off >>= 1) {
        ss_acc += __shfl_down(ss_acc, off);
        cs_acc += __shfl_down(cs_acc, off);
    }
    const int wave = tid >> 6;
    if ((tid & 63) == 0) { red[wave * 2] = ss_acc; red[wave * 2 + 1] = cs_acc; }
    __syncthreads();
    if (tid == 0) {
        slot[0] = red[0] + red[2] + red[4] + red[6];
        slot[1] = red[1] + red[3] + red[5] + red[7];
    }
}

// ================= scale-0: SSIM + in-register pooled pyramid =============
// Pooling lvl1/2 happens inside the v-pass load loop (zero re-read; R6/R8
// showed ANY second input read pass thrashes L2 at 4 blocks/CU).
// LDS = 38912 + 1024 + 256 + 32 = 40224 B <= 40960 -> 4 blocks/CU.
__global__ __launch_bounds__(256, 4) void ssim_scale0_kernel(
    const float* __restrict__ X, const float* __restrict__ Y,
    const float* __restrict__ kern, float* __restrict__ part,
    float* __restrict__ X1, float* __restrict__ Y1,
    float* __restrict__ X2, float* __restrict__ Y2,
    float* __restrict__ X3, float* __restrict__ Y3,
    float* __restrict__ X4, float* __restrict__ Y4)
{
    const int H = 512, W = 512;
    const int nc  = blockIdx.z;
    const int ch  = nc % 3;
    const int gx0 = blockIdx.x * TW;
    const int gy0 = blockIdx.y * TH;
    const int tid = threadIdx.x;

    __shared__ __align__(16) float vbuf[4][TH][IWC];
    __shared__ float pl2[2][8][16];
    __shared__ float pl3[2][4][8];
    __shared__ float red[8];

    float k[KS];
#pragma unroll
    for (int t = 0; t < KS; ++t) k[t] = kern[ch * KS + t];

    const float* Xp = X + (size_t)nc * H * W;
    const float* Yp = Y + (size_t)nc * H * W;

    const bool guard = (gx0 + IWC > W) || (gy0 + TH + 11 > H);
    if (guard) v_pass_pool<true >(Xp, Yp, k, gx0, gy0, tid, (vbuf_t*)vbuf, pl2, X1, Y1, X2, Y2, nc);
    else       v_pass_pool<false>(Xp, Yp, k, gx0, gy0, tid, (vbuf_t*)vbuf, pl2, X1, Y1, X2, Y2, nc);
    __syncthreads();

    float ss_acc = 0.f, cs_acc = 0.f;
    if (guard) h_pass<true >(k, H, W, gx0, gy0, tid, (vbuf_t*)vbuf, ss_acc, cs_acc);
    else       h_pass<false>(k, H, W, gx0, gy0, tid, (vbuf_t*)vbuf, ss_acc, cs_acc);

    // ---- levels 3&4 from tiny LDS staging ----
    if (tid < 64) {
        const int W8 = W >> 3;
        int a = tid >> 5, q = tid & 31;
        int r3 = q >> 3, c3 = q & 7;
        const float (*s)[16] = pl2[a];
        float v = 0.25f * (s[2*r3][2*c3] + s[2*r3][2*c3 + 1] +
                           s[2*r3 + 1][2*c3] + s[2*r3 + 1][2*c3 + 1]);
        pl3[a][r3][c3] = v;
        size_t d3 = (size_t)nc * W8 * W8 + (size_t)((gy0 >> 3) + r3) * W8 + ((gx0 >> 3) + c3);
        (a ? Y3 : X3)[d3] = v;
    }
    __syncthreads();
    if (tid < 16) {
        const int W16 = W >> 4;
        int a = tid >> 3, q = tid & 7;
        int r4 = q >> 2, c4 = q & 3;
        const float (*s)[8] = pl3[a];
        float v = 0.25f * (s[2*r4][2*c4] + s[2*r4][2*c4 + 1] +
                           s[2*r4 + 1][2*c4] + s[2*r4 + 1][2*c4 + 1]);
        size_t d4 = (size_t)nc * W16 * W16 + (size_t)((gy0 >> 4) + r4) * W16 + ((gx0 >> 4) + c4);
        (a ? Y4 : X4)[d4] = v;
    }

    int t = blockIdx.y * gridDim.x + blockIdx.x;
    block_reduce_store(ss_acc, cs_acc, tid, red,
                       part + ((size_t)nc * (gridDim.x * gridDim.y) + t) * 2);
}

// ================= merged scales 1-4 ======================================
__global__ __launch_bounds__(256, 4) void ssim_rest_kernel(
    const float* __restrict__ x1, const float* __restrict__ y1,
    const float* __restrict__ x2, const float* __restrict__ y2,
    const float* __restrict__ x3, const float* __restrict__ y3,
    const float* __restrict__ x4, const float* __restrict__ y4,
    const float* __restrict__ kern, float* __restrict__ part)
{
    const int z = blockIdx.z;
    const int tid = threadIdx.x;

    int img, bx, by, H, poff, nt, gw;
    const float *Xs, *Ys;
    if (z < 768)       { int r = z;        img = r >> 5; int t = r & 31; bx = t & 3; by = t >> 2; H = 256; Xs = x1; Ys = y1; poff = 6144; nt = 32; gw = 4; }
    else if (z < 960)  { int r = z - 768;  img = r >> 3; int t = r & 7;  bx = t & 1; by = t >> 1; H = 128; Xs = x2; Ys = y2; poff = 7680; nt = 8;  gw = 2; }
    else if (z < 1008) { int r = z - 960;  img = r >> 1; bx = 0; by = r & 1;         H = 64;  Xs = x3; Ys = y3; poff = 8064; nt = 2;  gw = 1; }
    else               { img = z - 1008;   bx = 0; by = 0;                           H = 32;  Xs = x4; Ys = y4; poff = 8160; nt = 1;  gw = 1; }
    const int W = H;
    const int gx0 = bx * TW, gy0 = by * TH;
    const int ch = img % 3;

    __shared__ __align__(16) float vbuf[4][TH][IWC];
    __shared__ float red[8];

    float k[KS];
#pragma unroll
    for (int t = 0; t < KS; ++t) k[t] = kern[ch * KS + t];

    const float* Xp = Xs + (size_t)img * H * W;
    const float* Yp = Ys + (size_t)img * H * W;

    const bool guard = (gx0 + IWC > W) || (gy0 + TH + 11 > H);
    if (guard) v_pass<true >(Xp, Yp, k, H, W, gx0, gy0, tid, (vbuf_t*)vbuf);
    else       v_pass<false>(Xp, Yp, k, H, W, gx0, gy0, tid, (vbuf_t*)vbuf);
    __syncthreads();

    float ss_acc = 0.f, cs_acc = 0.f;
    if (guard) h_pass<true >(k, H, W, gx0, gy0, tid, (vbuf_t*)vbuf, ss_acc, cs_acc);
    else       h_pass<false>(k, H, W, gx0, gy0, tid, (vbuf_t*)vbuf, ss_acc, cs_acc);

    int tl = by * gw + bx;
    block_reduce_store(ss_acc, cs_acc, tid, red,
                       part + poff + ((size_t)img * nt + tl) * 2);
}

// ================= finalize ==============================================
__global__ __launch_bounds__(256) void finalize_kernel(
    const float* __restrict__ part, const float* __restrict__ wts,
    float* __restrict__ out)
{
    __shared__ float smean[NCH][5];
    __shared__ float prods[NCH];
    const int ntiles[5] = {128, 32, 8, 2, 1};
    const int bases[5]  = {0, 6144, 7680, 8064, 8160};
    const float counts[5] = {252004.f, 60516.f, 13924.f, 2916.f, 484.f};
    int tid = threadIdx.x;

    for (int p = tid; p < NCH * 5; p += blockDim.x) {
        int s = p % 5, nc = p / 5;
        int nt = ntiles[s];
        const float* base = part + bases[s] + (size_t)nc * nt * 2;
        int sel = (s == 4) ? 0 : 1;
        float acc = 0.f;
        for (int t = 0; t < nt; ++t) acc += base[t * 2 + sel];
        smean[nc][s] = acc / counts[s];
    }
    __syncthreads();
    if (tid < NCH) {
        float pr = 1.f;
#pragma unroll
        for (int s = 0; s < 5; ++s) {
            float v = fmaxf(smean[tid][s], 0.f);
            pr *= powf(v, wts[s]);
        }
        prods[tid] = pr;
    }
    __syncthreads();
    if (tid == 0) {
        float m = 0.f;
        for (int i = 0; i < NCH; ++i) m += prods[i];
        out[0] = m / (float)NCH;
    }
}

extern "C" void kernel_launch(void* const* d_in, const int* in_sizes, int n_in,
                              void* d_out, int out_size, void* d_ws, size_t ws_size,
                              hipStream_t stream)
{
    const float* x    = (const float*)d_in[0];
    const float* y    = (const float*)d_in[1];
    const float* kern = (const float*)d_in[2];
    const float* wts  = (const float*)d_in[3];
    float* out = (float*)d_out;
    float* ws  = (float*)d_ws;

    size_t o = 0;
    float* x1 = ws + o; o += (size_t)NCH * 256 * 256;
    float* y1 = ws + o; o += (size_t)NCH * 256 * 256;
    float* x2 = ws + o; o += (size_t)NCH * 128 * 128;
    float* y2 = ws + o; o += (size_t)NCH * 128 * 128;
    float* x3 = ws + o; o += (size_t)NCH * 64 * 64;
    float* y3 = ws + o; o += (size_t)NCH * 64 * 64;
    float* x4 = ws + o; o += (size_t)NCH * 32 * 32;
    float* y4 = ws + o; o += (size_t)NCH * 32 * 32;
    float* part = ws + o;  // 8208 floats

    ssim_scale0_kernel<<<dim3(8, 16, NCH), 256, 0, stream>>>(
        x, y, kern, part, x1, y1, x2, y2, x3, y3, x4, y4);

    ssim_rest_kernel<<<dim3(1, 1, 1032), 256, 0, stream>>>(
        x1, y1, x2, y2, x3, y3, x4, y4, kern, part);

    finalize_kernel<<<1, 256, 0, stream>>>(part, wts, out);
}

// Round 10
// 70.512 us; speedup vs baseline: 1.2882x; 1.2882x over previous
//
#include <hip/hip_runtime.h>

#define NCH 24
#define KS 11
#define TH 32          // output rows per tile
#define TW 64          // output cols per tile
#define IWC 76         // LDS col stride (>= TW+10+2, mult of 4)

typedef float vbuf_t[TH][IWC];   // one field: 32 x 76

// ===== core tile: vertical-first sep-conv (4 fields) + SSIM ===============
// fields: 0 = x, 1 = y, 2 = xx+yy, 3 = xy
// Explicit 10-deep rotating register prefetch keeps ~20 loads in flight.
// POOL: level-1 pooling into pl[0..1023] pre-barrier (L2-hot re-read; OK at
// 3 blocks/CU — R7 measured FETCH 35.5 MB clean).
template<bool GUARD, bool POOL>
__device__ __forceinline__ void ssim_tile(
    const float* __restrict__ Xp, const float* __restrict__ Yp,
    const float* __restrict__ k, int H, int W, int gx0, int gy0, int tid,
    vbuf_t* vbuf, float* pl, float& ss_acc, float& cs_acc)
{
    // ---- vertical pass: 3 row-groups x 76 cols = 228 threads, 11 v-rows each
    if (tid < 3 * IWC) {
        const int c  = tid % IWC;
        const int rg = tid / IWC;
        const int r0 = rg * 11;              // v-rows r0..r0+10 (row 32 discarded)
        const int gc = gx0 + c;
        const bool cok = (!GUARD) || (gc < W);

        float acc[11][4];
#pragma unroll
        for (int i = 0; i < 11; ++i)
#pragma unroll
            for (int f = 0; f < 4; ++f) acc[i][f] = 0.f;

        const float* xptr = Xp + (size_t)(gy0 + r0) * W + gc;
        const float* yptr = Yp + (size_t)(gy0 + r0) * W + gc;

        // prologue: rows 0..9 into rotating buffer
        float xr[10], yr[10];
#pragma unroll
        for (int i = 0; i < 10; ++i) {
            if (GUARD) {
                const int gy = gy0 + r0 + i;
                xr[i] = 0.f; yr[i] = 0.f;
                if (cok && gy < H) { xr[i] = xptr[0]; yr[i] = yptr[0]; }
            } else {
                xr[i] = xptr[0]; yr[i] = yptr[0];
            }
            xptr += W; yptr += W;
        }

#pragma unroll
        for (int ri = 0; ri < 21; ++ri) {
            const int s = ri % 10;           // static under full unroll
            const float xv = xr[s], yv = yr[s];
            if (ri + 10 < 21) {              // prefetch row ri+10 into slot s
                if (GUARD) {
                    const int gy = gy0 + r0 + ri + 10;
                    xr[s] = 0.f; yr[s] = 0.f;
                    if (cok && gy < H) { xr[s] = xptr[0]; yr[s] = yptr[0]; }
                } else {
                    xr[s] = xptr[0]; yr[s] = yptr[0];
                }
                xptr += W; yptr += W;
            }

            const float sq = fmaf(yv, yv, xv * xv);   // xx+yy
            const float xy = xv * yv;
#pragma unroll
            for (int rv = 0; rv < 11; ++rv) {
                if (rv < (ri > 10 ? ri - 10 : 0)) continue;   // compile-time folded
                if (rv > (ri < 10 ? ri : 10)) continue;
                const float kt = k[ri - rv];
                acc[rv][0] += kt * xv;
                acc[rv][1] += kt * yv;
                acc[rv][2] += kt * sq;
                acc[rv][3] += kt * xy;
            }
        }
#pragma unroll
        for (int rv = 0; rv < 11; ++rv) {
            const int r = r0 + rv;
            if (r < TH) {
#pragma unroll
                for (int f = 0; f < 4; ++f)
                    vbuf[f][r][c] = acc[rv][f];
            }
        }
    }

    // ---- level-1 2x2 pooling while input lines are L2-hot (pre-barrier) ----
    if (POOL) {
        for (int p = tid; p < 512; p += 256) {      // 16r x 32c per array
            int pr = p >> 5, pc = p & 31;
            int sr = gy0 + 2 * pr, sc = gx0 + 2 * pc;
            const float* xb = Xp + (size_t)sr * W + sc;
            const float* yb = Yp + (size_t)sr * W + sc;
            pl[p]       = 0.25f * (xb[0] + xb[1] + xb[W] + xb[W + 1]);
            pl[512 + p] = 0.25f * (yb[0] + yb[1] + yb[W] + yb[W + 1]);
        }
    }
    __syncthreads();

    // ---- horizontal pass: b128 LDS reads + SSIM
    const float c1 = 1e-4f, c2 = 9e-4f;
    const int row = tid >> 3;
    const int cg  = tid & 7;
    const int c0  = cg * 8;
    const bool rowok = (!GUARD) || ((gy0 + row) <= (H - KS));

    float hacc[4][8];
#pragma unroll
    for (int f = 0; f < 4; ++f)
#pragma unroll
        for (int j = 0; j < 8; ++j) hacc[f][j] = 0.f;

#pragma unroll
    for (int f = 0; f < 4; ++f) {
        const float4* vp = reinterpret_cast<const float4*>(&vbuf[f][row][c0]);
        float4 q0 = vp[0], q1 = vp[1], q2 = vp[2], q3 = vp[3], q4 = vp[4];
        float v[20] = {q0.x,q0.y,q0.z,q0.w, q1.x,q1.y,q1.z,q1.w,
                       q2.x,q2.y,q2.z,q2.w, q3.x,q3.y,q3.z,q3.w,
                       q4.x,q4.y,q4.z,q4.w};
#pragma unroll
        for (int j = 0; j < 8; ++j)
#pragma unroll
            for (int t = 0; t < KS; ++t)
                hacc[f][j] += k[t] * v[j + t];
    }

#pragma unroll
    for (int j = 0; j < 8; ++j) {
        bool ok = rowok && ((!GUARD) || ((gx0 + c0 + j) <= (W - KS)));
        if (ok) {
            float mx = hacc[0][j], my = hacc[1][j];
            float S = hacc[2][j], vxy = hacc[3][j];
            float mxx = mx * mx, myy = my * my, mxy = mx * my;
            float msum = mxx + myy;
            float sxy = vxy - mxy, ssum = S - msum;
            float cs = (2.f * sxy + c2) * __builtin_amdgcn_rcpf(ssum + c2);
            float ssv = (2.f * mxy + c1) * __builtin_amdgcn_rcpf(msum + c1) * cs;
            ss_acc += ssv; cs_acc += cs;
        }
    }
}

__device__ __forceinline__ void block_reduce_store(
    float ss_acc, float cs_acc, int tid, float* red, float* slot)
{
    for (int off = 32; off > 0; off >>= 1) {
        ss_acc += __shfl_down(ss_acc, off);
        cs_acc += __shfl_down(cs_acc, off);
    }
    const int wave = tid >> 6;
    if ((tid & 63) == 0) { red[wave * 2] = ss_acc; red[wave * 2 + 1] = cs_acc; }
    __syncthreads();
    if (tid == 0) {
        slot[0] = red[0] + red[2] + red[4] + red[6];
        slot[1] = red[1] + red[3] + red[5] + red[7];
    }
}

// ================= scale-0: SSIM + full pooled-pyramid epilogue ===========
// LB(256,3): 3 blocks/CU, VGPR cap 128 (LB(256,4) made the compiler target
// the 64-VGPR tier -> scratch spills -> HBM traffic explosion, R8/R9).
__global__ __launch_bounds__(256, 3) void ssim_scale0_kernel(
    const float* __restrict__ X, const float* __restrict__ Y,
    const float* __restrict__ kern, float* __restrict__ part,
    float* __restrict__ X1, float* __restrict__ Y1,
    float* __restrict__ X2, float* __restrict__ Y2,
    float* __restrict__ X3, float* __restrict__ Y3,
    float* __restrict__ X4, float* __restrict__ Y4)
{
    const int H = 512, W = 512;
    const int nc  = blockIdx.z;
    const int ch  = nc % 3;
    const int gx0 = blockIdx.x * TW;
    const int gy0 = blockIdx.y * TH;
    const int tid = threadIdx.x;

    __shared__ __align__(16) float vbuf[4][TH][IWC];
    __shared__ float pl[1344];   // lvl1: [0,1024) lvl2: [1024,1280) lvl3: [1280,1344)
    __shared__ float red[8];

    float k[KS];
#pragma unroll
    for (int t = 0; t < KS; ++t) k[t] = kern[ch * KS + t];

    const float* Xp = X + (size_t)nc * H * W;
    const float* Yp = Y + (size_t)nc * H * W;

    float ss_acc = 0.f, cs_acc = 0.f;
    const bool guard = (gx0 + IWC > W) || (gy0 + TH + 11 > H);
    if (guard) ssim_tile<true , true>(Xp, Yp, k, H, W, gx0, gy0, tid, (vbuf_t*)vbuf, pl, ss_acc, cs_acc);
    else       ssim_tile<false, true>(Xp, Yp, k, H, W, gx0, gy0, tid, (vbuf_t*)vbuf, pl, ss_acc, cs_acc);

    // ---- write level 1 to global + build levels 2-4 from LDS (no global re-read)
    {
        const int W2 = W >> 1;
        for (int p = tid; p < 512; p += 256) {
            int pr = p >> 5, pc = p & 31;
            size_t di = (size_t)nc * W2 * W2 + (size_t)((gy0 >> 1) + pr) * W2 + ((gx0 >> 1) + pc);
            X1[di] = pl[p];
            Y1[di] = pl[512 + p];
        }
    }
    {
        const int W4 = W >> 2;                         // level 2: 8r x 16c per array
        int a = tid >> 7, p = tid & 127;
        int pr = p >> 4, pc = p & 15;
        const float* src = pl + a * 512;
        float v = 0.25f * (src[(2*pr)*32 + 2*pc] + src[(2*pr)*32 + 2*pc + 1] +
                           src[(2*pr+1)*32 + 2*pc] + src[(2*pr+1)*32 + 2*pc + 1]);
        pl[1024 + a * 128 + p] = v;
        size_t di = (size_t)nc * W4 * W4 + (size_t)((gy0 >> 2) + pr) * W4 + ((gx0 >> 2) + pc);
        (a ? Y2 : X2)[di] = v;
    }
    __syncthreads();
    if (tid < 64) {
        const int W8 = W >> 3;                         // level 3: 4r x 8c per array
        int a = tid >> 5, p = tid & 31;
        int pr = p >> 3, pc = p & 7;
        const float* src = pl + 1024 + a * 128;
        float v = 0.25f * (src[(2*pr)*16 + 2*pc] + src[(2*pr)*16 + 2*pc + 1] +
                           src[(2*pr+1)*16 + 2*pc] + src[(2*pr+1)*16 + 2*pc + 1]);
        pl[1280 + a * 32 + p] = v;
        size_t di = (size_t)nc * W8 * W8 + (size_t)((gy0 >> 3) + pr) * W8 + ((gx0 >> 3) + pc);
        (a ? Y3 : X3)[di] = v;
    }
    __syncthreads();
    if (tid < 16) {
        const int W16 = W >> 4;                        // level 4: 2r x 4c per array
        int a = tid >> 3, p = tid & 7;
        int pr = p >> 2, pc = p & 3;
        const float* src = pl + 1280 + a * 32;
        float v = 0.25f * (src[(2*pr)*8 + 2*pc] + src[(2*pr)*8 + 2*pc + 1] +
                           src[(2*pr+1)*8 + 2*pc] + src[(2*pr+1)*8 + 2*pc + 1]);
        size_t di = (size_t)nc * W16 * W16 + (size_t)((gy0 >> 4) + pr) * W16 + ((gx0 >> 4) + pc);
        (a ? Y4 : X4)[di] = v;
    }

    int t = blockIdx.y * gridDim.x + blockIdx.x;
    block_reduce_store(ss_acc, cs_acc, tid, red,
                       part + ((size_t)nc * (gridDim.x * gridDim.y) + t) * 2);
}

// ================= merged scales 1-4 ======================================
__global__ __launch_bounds__(256, 3) void ssim_rest_kernel(
    const float* __restrict__ x1, const float* __restrict__ y1,
    const float* __restrict__ x2, const float* __restrict__ y2,
    const float* __restrict__ x3, const float* __restrict__ y3,
    const float* __restrict__ x4, const float* __restrict__ y4,
    const float* __restrict__ kern, float* __restrict__ part)
{
    const int z = blockIdx.z;
    const int tid = threadIdx.x;

    int img, bx, by, H, poff, nt, gw;
    const float *Xs, *Ys;
    if (z < 768)       { int r = z;        img = r >> 5; int t = r & 31; bx = t & 3; by = t >> 2; H = 256; Xs = x1; Ys = y1; poff = 6144; nt = 32; gw = 4; }
    else if (z < 960)  { int r = z - 768;  img = r >> 3; int t = r & 7;  bx = t & 1; by = t >> 1; H = 128; Xs = x2; Ys = y2; poff = 7680; nt = 8;  gw = 2; }
    else if (z < 1008) { int r = z - 960;  img = r >> 1; bx = 0; by = r & 1;         H = 64;  Xs = x3; Ys = y3; poff = 8064; nt = 2;  gw = 1; }
    else               { img = z - 1008;   bx = 0; by = 0;                           H = 32;  Xs = x4; Ys = y4; poff = 8160; nt = 1;  gw = 1; }
    const int W = H;
    const int gx0 = bx * TW, gy0 = by * TH;
    const int ch = img % 3;

    __shared__ __align__(16) float vbuf[4][TH][IWC];
    __shared__ float red[8];

    float k[KS];
#pragma unroll
    for (int t = 0; t < KS; ++t) k[t] = kern[ch * KS + t];

    const float* Xp = Xs + (size_t)img * H * W;
    const float* Yp = Ys + (size_t)img * H * W;

    float ss_acc = 0.f, cs_acc = 0.f;
    const bool guard = (gx0 + IWC > W) || (gy0 + TH + 11 > H);
    if (guard) ssim_tile<true , false>(Xp, Yp, k, H, W, gx0, gy0, tid, (vbuf_t*)vbuf, nullptr, ss_acc, cs_acc);
    else       ssim_tile<false, false>(Xp, Yp, k, H, W, gx0, gy0, tid, (vbuf_t*)vbuf, nullptr, ss_acc, cs_acc);

    int tl = by * gw + bx;
    block_reduce_store(ss_acc, cs_acc, tid, red,
                       part + poff + ((size_t)img * nt + tl) * 2);
}

// ================= finalize ==============================================
__global__ __launch_bounds__(256) void finalize_kernel(
    const float* __restrict__ part, const float* __restrict__ wts,
    float* __restrict__ out)
{
    __shared__ float smean[NCH][5];
    __shared__ float prods[NCH];
    const int ntiles[5] = {128, 32, 8, 2, 1};
    const int bases[5]  = {0, 6144, 7680, 8064, 8160};
    const float counts[5] = {252004.f, 60516.f, 13924.f, 2916.f, 484.f};
    int tid = threadIdx.x;

    for (int p = tid; p < NCH * 5; p += blockDim.x) {
        int s = p % 5, nc = p / 5;
        int nt = ntiles[s];
        const float* base = part + bases[s] + (size_t)nc * nt * 2;
        int sel = (s == 4) ? 0 : 1;   // ss for last scale, cs otherwise
        float acc = 0.f;
        for (int t = 0; t < nt; ++t) acc += base[t * 2 + sel];
        smean[nc][s] = acc / counts[s];
    }
    __syncthreads();
    if (tid < NCH) {
        float pr = 1.f;
#pragma unroll
        for (int s = 0; s < 5; ++s) {
            float v = fmaxf(smean[tid][s], 0.f);
            pr *= powf(v, wts[s]);
        }
        prods[tid] = pr;
    }
    __syncthreads();
    if (tid == 0) {
        float m = 0.f;
        for (int i = 0; i < NCH; ++i) m += prods[i];
        out[0] = m / (float)NCH;
    }
}

extern "C" void kernel_launch(void* const* d_in, const int* in_sizes, int n_in,
                              void* d_out, int out_size, void* d_ws, size_t ws_size,
                              hipStream_t stream)
{
    const float* x    = (const float*)d_in[0];
    const float* y    = (const float*)d_in[1];
    const float* kern = (const float*)d_in[2];
    const float* wts  = (const float*)d_in[3];
    float* out = (float*)d_out;
    float* ws  = (float*)d_ws;

    size_t o = 0;
    float* x1 = ws + o; o += (size_t)NCH * 256 * 256;
    float* y1 = ws + o; o += (size_t)NCH * 256 * 256;
    float* x2 = ws + o; o += (size_t)NCH * 128 * 128;
    float* y2 = ws + o; o += (size_t)NCH * 128 * 128;
    float* x3 = ws + o; o += (size_t)NCH * 64 * 64;
    float* y3 = ws + o; o += (size_t)NCH * 64 * 64;
    float* x4 = ws + o; o += (size_t)NCH * 32 * 32;
    float* y4 = ws + o; o += (size_t)NCH * 32 * 32;
    float* part = ws + o;  // 8208 floats

    ssim_scale0_kernel<<<dim3(8, 16, NCH), 256, 0, stream>>>(
        x, y, kern, part, x1, y1, x2, y2, x3, y3, x4, y4);

    ssim_rest_kernel<<<dim3(1, 1, 1032), 256, 0, stream>>>(
        x1, y1, x2, y2, x3, y3, x4, y4, kern, part);

    finalize_kernel<<<1, 256, 0, stream>>>(part, wts, out);
}